// Round 8
// baseline (657.812 us; speedup 1.0000x reference)
//
#include <hip/hip_runtime.h>
#include <hip/hip_bf16.h>

#define NN    9216      /* 96*96   */
#define MM    2304      /* 48*48   */
#define HW    36864     /* 192*192 */
#define SLABF 4718592   /* f32 per batch slab of output: 128*192*192 */
#define TEMPF 5.0f

/* d_out f32 offsets (scratch; lifetimes verified):
   x    [0        , 4718592)   dead after theta/phi convs; then attn PO partials
   y    [4718592  , 9437184)   dead after g conv; then attn m/l partials
   th   [9437184  , 11796480)  dead after attn
   tp   [11796480 , 14155776)  pre-pool temp, dead after pools
   ph   [14155776 , 14745600)  phiT bf16 [b][2304][64] (uses half region)
   g    [14745600 , 15335424)  g bf16 [b][64][2304]   (uses half region)
   omap [15335424 , 17694720)  merged attn out, read by oconv
   ofin : swizzled into plane-0..31 prefix of each batch slab (race-free k_up)
   Order: attn(writes PO@X, ML@Y) -> amerge(reads PO/ML, writes OM) ->
          oconv(reads OM, writes slab prefixes over X/Y/TH/PH/G) -> up. */
#define OFF_X   0
#define OFF_Y   4718592
#define OFF_TH  9437184
#define OFF_TP  11796480
#define OFF_PH  14155776
#define OFF_G   14745600
#define OFF_OM  15335424
#define POSZ    2359296   /* 4*64*9216: one split's partial O */
#define MLSZ    73728     /* 2*4*9216: m (or l) for both splits */

typedef unsigned short u16;
typedef unsigned int   u32;
typedef __attribute__((ext_vector_type(8))) short bf16x8;
typedef __attribute__((ext_vector_type(4))) float f32x4;

__device__ __forceinline__ u16 f2bf(float f){
  u32 u; __builtin_memcpy(&u,&f,4);
  u32 lsb = (u>>16)&1u; u += 0x7fffu + lsb;   /* RNE */
  return (u16)(u>>16);
}
__device__ __forceinline__ u32 pkbf(float a, float b){
  union { __hip_bfloat162 h; u32 u; } v;
  v.h = __float22bfloat162_rn(make_float2(a,b));
  return v.u;
}
/* async global->LDS 16B; LDS dest = wave-uniform base + lane*16 */
__device__ __forceinline__ void gload16(const float* g, float* l){
  __builtin_amdgcn_global_load_lds(
      (const __attribute__((address_space(1))) void*)g,
      (__attribute__((address_space(3))) void*)l, 16, 0, 0);
}

/* ---- down conv k=2 s=2, 128->128, f32 ----
   R7 rewrite of the VALU-issue path (R3 was 59us VALU for a 31us FMA floor):
   (a) explicit fmaf chains: R3's "acc += a*b+c*d+e*f+g*h" compiled per C
       eval order to mul+3fma+add (5 ops/group, +25% issue). Now 96 v_fmac/c.
   (b) global_load_lds staging, LDS linear [32c][2r][96col] (lane-order =
       6x 4KB issues of 256 lanes x 16B): zero staging VALU, no repack.
       ds_read_b128 pattern: 8 distinct 16B addrs/wave, banks
       {0,12,24,4,16,28,8,20} - conflict-free.
   (c) stage-after-barrier: next chunk issued right after __syncthreads so
       the loads overlap the 32-c compute; the NEXT barrier's implicit
       vmcnt(0) drains them (issuing before the barrier would stall on them).
   (d) #pragma unroll 8: immediate-folded ds/weight offsets. */
__global__ __launch_bounds__(256) void k_down(const float* __restrict__ in,
    const float* __restrict__ w, const float* __restrict__ bias, float* __restrict__ out)
{
  __shared__ __align__(16) float xs[2][6144];   /* [32c][2r][96col] x dbuf, 48KB */
  int blk = blockIdx.x;
  int jt = blk & 1;
  int r1 = blk >> 1;
  int i  = r1 % 96; int b = r1 / 96;
  int t  = threadIdx.x;
  int wvb = (t >> 6) << 8;          /* wave LDS f32 base: wv*256 */

  const float* src = in + (size_t)b*128*HW + (size_t)(2*i)*192 + jt*96;

  /* per-lane global f32 offsets for the 6 stage issues of a chunk:
     flat chunk idx = e*1024 + t*4 -> (c, r, col) -> c*HW + r*192 + col */
  int goff[6];
  #pragma unroll
  for (int e = 0; e < 6; e++) {
    int idx = e*1024 + t*4;
    int c   = idx / 192;
    int rem = idx - c*192;
    int r   = rem / 96;
    int col = rem - r*96;
    goff[e] = c*HW + r*192 + col;
  }

  /* stage chunk 0 */
  #pragma unroll
  for (int e = 0; e < 6; e++)
    gload16(src + goff[e], &xs[0][e*1024 + wvb]);

  int og = t >> 3, jg = t & 7;       /* 32 og x 4 o ; 8 jg x 6 out cols */
  int o0 = og * 4;
  float acc[4][6];
  #pragma unroll
  for (int oo = 0; oo < 4; oo++)
    #pragma unroll
    for (int jj = 0; jj < 6; jj++) acc[oo][jj] = 0.f;

  const float* wbase = w + (size_t)o0*512;   /* w[o][c][4] */

  int buf = 0;
  for (int ch = 0; ch < 4; ch++) {
    __syncthreads();                 /* drains stage(ch); prev compute done */
    if (ch < 3) {                    /* async prefetch, overlaps compute */
      const float* gs = src + (size_t)((ch+1)*32)*HW;
      #pragma unroll
      for (int e = 0; e < 6; e++)
        gload16(gs + goff[e], &xs[buf^1][e*1024 + wvb]);
    }

    const float* xb = xs[buf];
    const float* wc = wbase + ch*128;       /* + c*4 per channel */
    #pragma unroll 8
    for (int c = 0; c < 32; c++) {
      const float* xp = xb + c*192 + jg*12;
      float4 r0a = *(const float4*)(xp);
      float4 r0b = *(const float4*)(xp + 4);
      float4 r0c = *(const float4*)(xp + 8);
      float4 r1a = *(const float4*)(xp + 96);
      float4 r1b = *(const float4*)(xp + 100);
      float4 r1c = *(const float4*)(xp + 104);
      #pragma unroll
      for (int oo = 0; oo < 4; oo++) {
        float4 wv4 = *(const float4*)(wc + oo*512 + c*4);   /* w00 w01 w10 w11 */
        float a;
        a=acc[oo][0]; a=fmaf(r0a.x,wv4.x,a); a=fmaf(r0a.y,wv4.y,a); a=fmaf(r1a.x,wv4.z,a); a=fmaf(r1a.y,wv4.w,a); acc[oo][0]=a;
        a=acc[oo][1]; a=fmaf(r0a.z,wv4.x,a); a=fmaf(r0a.w,wv4.y,a); a=fmaf(r1a.z,wv4.z,a); a=fmaf(r1a.w,wv4.w,a); acc[oo][1]=a;
        a=acc[oo][2]; a=fmaf(r0b.x,wv4.x,a); a=fmaf(r0b.y,wv4.y,a); a=fmaf(r1b.x,wv4.z,a); a=fmaf(r1b.y,wv4.w,a); acc[oo][2]=a;
        a=acc[oo][3]; a=fmaf(r0b.z,wv4.x,a); a=fmaf(r0b.w,wv4.y,a); a=fmaf(r1b.z,wv4.z,a); a=fmaf(r1b.w,wv4.w,a); acc[oo][3]=a;
        a=acc[oo][4]; a=fmaf(r0c.x,wv4.x,a); a=fmaf(r0c.y,wv4.y,a); a=fmaf(r1c.x,wv4.z,a); a=fmaf(r1c.y,wv4.w,a); acc[oo][4]=a;
        a=acc[oo][5]; a=fmaf(r0c.z,wv4.x,a); a=fmaf(r0c.w,wv4.y,a); a=fmaf(r1c.z,wv4.z,a); a=fmaf(r1c.w,wv4.w,a); acc[oo][5]=a;
      }
    }
    buf ^= 1;
  }

  /* epilogue: out[b][o][i][jt*48 + jg*6 + {0..5}] (8B-aligned float2 stores) */
  #pragma unroll
  for (int oo = 0; oo < 4; oo++) {
    int o = o0 + oo;
    float bv = bias[o];
    float* op = out + ((size_t)(b*128 + o))*NN + i*96 + jt*48 + jg*6;
    *(float2*)(op)     = make_float2(acc[oo][0] + bv, acc[oo][1] + bv);
    *(float2*)(op + 2) = make_float2(acc[oo][2] + bv, acc[oo][3] + bv);
    *(float2*)(op + 4) = make_float2(acc[oo][4] + bv, acc[oo][5] + bv);
  }
}

/* ---- 1x1 conv 128->64: out[b][cc][n] = sum_c W[cc][c]*X[b][c][n] ---- */
__global__ __launch_bounds__(256) void k_conv(const float* __restrict__ X,
    const float* __restrict__ WG, float* __restrict__ out)
{
  __shared__ __align__(16) float Xs[128*32];   /* [c][32 n] 16KB */
  __shared__ __align__(16) float wt[128*64];   /* [c][cc]   32KB */
  int b  = blockIdx.x / 288;
  int n0 = (blockIdx.x % 288) * 32;
  int t  = threadIdx.x;
  for (int idx = t; idx < 8192; idx += 256) {
    int c = idx >> 6, cc = idx & 63;
    wt[idx] = WG[cc*128 + c];
  }
  for (int idx = t; idx < 1024; idx += 256) {
    int c = idx >> 3, wq = idx & 7;
    ((float4*)Xs)[idx] = *(const float4*)&X[((size_t)(b*128 + c))*NN + n0 + wq*4];
  }
  __syncthreads();
  int n = t & 31, og = t >> 5;
  float acc[8];
  #pragma unroll
  for (int k = 0; k < 8; k++) acc[k] = 0.f;
  for (int c = 0; c < 128; c++) {
    float xv = Xs[(c<<5) + n];
    const float* wrow = wt + (c<<6) + og*8;
    float4 wa = *(const float4*)wrow;
    float4 wb = *(const float4*)(wrow + 4);
    acc[0]+=wa.x*xv; acc[1]+=wa.y*xv; acc[2]+=wa.z*xv; acc[3]+=wa.w*xv;
    acc[4]+=wb.x*xv; acc[5]+=wb.y*xv; acc[6]+=wb.z*xv; acc[7]+=wb.w*xv;
  }
  #pragma unroll
  for (int k = 0; k < 8; k++)
    out[((size_t)(b*64 + og*8 + k))*NN + n0 + n] = acc[k];
}

/* ---- phi path: 2x2 maxpool + transpose + bf16 cast.
   in: tp f32 [b][64][96][96] -> out: phiT bf16 [b][2304 k][64 c] ---- */
__global__ __launch_bounds__(256) void k_poolT(const float* __restrict__ in, u16* __restrict__ out)
{
  __shared__ float ps[48*68];    /* [J][cc] pad->68, 12.75KB */
  int blk = blockIdx.x;
  int I = blk % 48, b = blk / 48;
  int t = threadIdx.x;
  int cc = t >> 2, jq = t & 3;
  const float* base = in + ((size_t)(b*64 + cc))*NN + (size_t)(2*I)*96;
  #pragma unroll
  for (int j = 0; j < 12; j++) {
    int J = jq*12 + j;
    const float* p = base + 2*J;
    float2 a = *(const float2*)p;
    float2 c = *(const float2*)(p + 96);
    ps[J*68 + cc] = fmaxf(fmaxf(a.x, a.y), fmaxf(c.x, c.y));
  }
  __syncthreads();
  u32* op = (u32*)out + ((size_t)b*2304 + I*48)*32;   /* 48 rows x 32 u32 */
  for (int idx = t; idx < 1536; idx += 256) {
    int row = idx >> 5, pr = idx & 31;
    op[row*32 + pr] = pkbf(ps[row*68 + 2*pr], ps[row*68 + 2*pr + 1]);
  }
}

/* ---- g path: 2x2 maxpool + bf16 cast (layout preserved).
   in: tp f32 [b][64][96][96] -> out: g bf16 [b][64][2304]. ---- */
__global__ __launch_bounds__(256) void k_poolB(const float* __restrict__ in, u16* __restrict__ out)
{
  int t = blockIdx.x*256 + threadIdx.x;   /* 294912 */
  int pr = t % 24; int r = t / 24;
  int I = r % 48; r /= 48;
  int cc = r & 63, b = r >> 6;
  const float* p = in + ((size_t)(b*64 + cc))*NN + (size_t)(2*I)*96 + 4*pr;
  float4 r0 = *(const float4*)p;
  float4 r1 = *(const float4*)(p + 96);
  float m0 = fmaxf(fmaxf(r0.x, r0.y), fmaxf(r1.x, r1.y));
  float m1 = fmaxf(fmaxf(r0.z, r0.w), fmaxf(r1.z, r1.w));
  ((u32*)out)[((size_t)(b*64 + cc))*1152 + I*24 + pr] = pkbf(m0, m1);
}

/* ---- MFMA flash attention, split-K x2 (bf16 inputs pre-converted).
   grid = b(4) x ks(2) x qtile(144) = 1152 blocks (~4.5/CU, LDS cap 5).
   Outputs UNNORMALIZED partial O to PO[ks], (m,l) to ML; k_amerge combines. ---- */
__global__ __launch_bounds__(256) void k_attn(const float* __restrict__ TH,
    const u16* __restrict__ PHT, const u16* __restrict__ GB,
    float* __restrict__ PO, float* __restrict__ ML)
{
  __shared__ __align__(16) u16 sm[13824];   /* 27648 B */
  int t = threadIdx.x;
  int lane = t & 63, wv = t >> 6;
  int quad = lane >> 4, l15 = lane & 15;
  int id = blockIdx.x;
  int b   = id / 288;
  int rem = id % 288;
  int ks  = rem / 144;
  int q0  = (rem % 144) * 64;
  int qw  = q0 + wv*16;

  /* theta A-fragments, TEMP pre-scaled: A[q=l15][c=half*32+quad*8+j] */
  bf16x8 afrag[2];
  #pragma unroll
  for (int h = 0; h < 2; h++)
    #pragma unroll
    for (int j = 0; j < 8; j++) {
      float v = TEMPF * TH[((size_t)(b*64 + h*32 + quad*8 + j))*NN + qw + l15];
      afrag[h][j] = (short)f2bf(v);
    }

  f32x4 oacc[4];
  #pragma unroll
  for (int ct = 0; ct < 4; ct++)
    #pragma unroll
    for (int r = 0; r < 4; r++) oacc[ct][r] = 0.f;
  float m_r[4], l_r[4];
  #pragma unroll
  for (int r = 0; r < 4; r++) { m_r[r] = -3.0e38f; l_r[r] = 0.f; }

  int k0end = ks*1152 + 1152;
  for (int k0 = ks*1152; k0 < k0end; k0 += 64) {
    __syncthreads();                       /* prev PV done before overwrite */
    /* stage phi_T[k][c]: 64 rows x 128B, 2 uint4/thread, fully coalesced */
    #pragma unroll
    for (int s = 0; s < 2; s++) {
      int idx = t + s*256;
      int row = idx >> 3, q = idx & 7;
      uint4 v = ((const uint4*)(PHT + ((size_t)(b*2304 + k0 + row))*64))[q];
      *(uint4*)&sm[row*72 + q*8] = v;
    }
    /* stage g[cc][k]: 64 rows x 128B */
    #pragma unroll
    for (int s = 0; s < 2; s++) {
      int idx = t + s*256;
      int row = idx >> 3, q = idx & 7;
      uint4 v = *(const uint4*)(GB + (size_t)(b*64 + row)*2304 + k0 + q*8);
      *(uint4*)&sm[4608 + row*72 + q*8] = v;
    }
    __syncthreads();

    /* QK^T: 4 key-tiles x (2 MFMA over c) -> S[q=quad*4+r][key=kt*16+l15] */
    f32x4 s[4];
    #pragma unroll
    for (int kt = 0; kt < 4; kt++) {
      f32x4 acc;
      #pragma unroll
      for (int r = 0; r < 4; r++) acc[r] = 0.f;
      #pragma unroll
      for (int h = 0; h < 2; h++) {
        bf16x8 bfrag = *(const bf16x8*)&sm[(kt*16 + l15)*72 + h*32 + quad*8];
        acc = __builtin_amdgcn_mfma_f32_16x16x32_bf16(afrag[h], bfrag, acc, 0, 0, 0);
      }
      s[kt] = acc;
    }

    /* online softmax, per row r (q = quad*4+r), reduce over 16 lanes + 4 tiles */
    float al[4];
    #pragma unroll
    for (int r = 0; r < 4; r++) {
      float mx = fmaxf(fmaxf(s[0][r], s[1][r]), fmaxf(s[2][r], s[3][r]));
      #pragma unroll
      for (int d = 1; d < 16; d <<= 1) mx = fmaxf(mx, __shfl_xor(mx, d));
      float mn = fmaxf(m_r[r], mx);
      float a  = __expf(m_r[r] - mn);
      m_r[r] = mn;
      float ps = 0.f;
      #pragma unroll
      for (int kt = 0; kt < 4; kt++) {
        float p = __expf(s[kt][r] - mn);
        s[kt][r] = p; ps += p;
      }
      #pragma unroll
      for (int d = 1; d < 16; d <<= 1) ps += __shfl_xor(ps, d);
      l_r[r] = l_r[r]*a + ps;
      al[r] = a;
    }
    /* P -> per-wave LDS (bf16), rescale O */
    #pragma unroll
    for (int kt = 0; kt < 4; kt++)
      #pragma unroll
      for (int r = 0; r < 4; r++)
        sm[9216 + wv*1152 + (quad*4 + r)*72 + kt*16 + l15] = f2bf(s[kt][r]);
    #pragma unroll
    for (int ct = 0; ct < 4; ct++)
      #pragma unroll
      for (int r = 0; r < 4; r++) oacc[ct][r] *= al[r];

    /* PV: A = P[q=l15][key=h*32+quad*8+j], B = g[key][cc=ct*16+l15] */
    bf16x8 pf[2];
    #pragma unroll
    for (int h = 0; h < 2; h++)
      pf[h] = *(const bf16x8*)&sm[9216 + wv*1152 + l15*72 + h*32 + quad*8];
    #pragma unroll
    for (int ct = 0; ct < 4; ct++)
      #pragma unroll
      for (int h = 0; h < 2; h++) {
        bf16x8 gf = *(const bf16x8*)&sm[4608 + (ct*16 + l15)*72 + h*32 + quad*8];
        oacc[ct] = __builtin_amdgcn_mfma_f32_16x16x32_bf16(pf[h], gf, oacc[ct], 0, 0, 0);
      }
  }

  __syncthreads();   /* all waves done with phi/g/P regions */
  /* m,l per query (one lane per row) */
  if (l15 == 0) {
    #pragma unroll
    for (int r = 0; r < 4; r++) {
      int qg = qw + quad*4 + r;
      ML[(size_t)(ks*4 + b)*9216 + qg]         = m_r[r];
      ML[MLSZ + (size_t)(ks*4 + b)*9216 + qg]  = l_r[r];
    }
  }
  /* raw (unnormalized) O, transposed through LDS for coalesced store */
  float* ol = (float*)sm + wv*1280;      /* [cc 64][20] */
  #pragma unroll
  for (int ct = 0; ct < 4; ct++)
    #pragma unroll
    for (int r = 0; r < 4; r++)
      ol[(ct*16 + l15)*20 + quad*4 + r] = oacc[ct][r];
  __syncthreads();
  const float* orow = ol + lane*20;      /* cc = lane */
  float4 v0 = *(const float4*)(orow);
  float4 v1 = *(const float4*)(orow + 4);
  float4 v2 = *(const float4*)(orow + 8);
  float4 v3 = *(const float4*)(orow + 12);
  float* dst = PO + (size_t)ks*POSZ + ((size_t)(b*64 + lane))*NN + qw;
  *(float4*)(dst)      = v0;
  *(float4*)(dst + 4)  = v1;
  *(float4*)(dst + 8)  = v2;
  *(float4*)(dst + 12) = v3;
}

/* ---- combine 2 split-K partials: O = sum(e^{mi-M} POi) / sum(e^{mi-M} li) ---- */
__global__ __launch_bounds__(256) void k_amerge(const float* __restrict__ PO,
    const float* __restrict__ ML, float* __restrict__ OUT)
{
  int idx = blockIdx.x*256 + threadIdx.x;   /* 589824 float4s */
  size_t flat = (size_t)idx*4;
  int bc = (int)(flat / NN);
  int n  = (int)(flat - (size_t)bc*NN);
  int b  = bc >> 6;
  float4 p0 = *(const float4*)&PO[flat];
  float4 p1 = *(const float4*)&PO[POSZ + flat];
  const float* m0p = ML + (size_t)b*9216 + n;
  const float* m1p = ML + (size_t)(4 + b)*9216 + n;
  const float* l0p = ML + MLSZ + (size_t)b*9216 + n;
  const float* l1p = ML + MLSZ + (size_t)(4 + b)*9216 + n;
  float4 m0 = *(const float4*)m0p, m1 = *(const float4*)m1p;
  float4 l0 = *(const float4*)l0p, l1 = *(const float4*)l1p;
  float4 r;
  {
    float M = fmaxf(m0.x, m1.x); float a0 = __expf(m0.x - M), a1 = __expf(m1.x - M);
    r.x = (a0*p0.x + a1*p1.x) / (a0*l0.x + a1*l1.x);
  }
  {
    float M = fmaxf(m0.y, m1.y); float a0 = __expf(m0.y - M), a1 = __expf(m1.y - M);
    r.y = (a0*p0.y + a1*p1.y) / (a0*l0.y + a1*l1.y);
  }
  {
    float M = fmaxf(m0.z, m1.z); float a0 = __expf(m0.z - M), a1 = __expf(m1.z - M);
    r.z = (a0*p0.z + a1*p1.z) / (a0*l0.z + a1*l1.z);
  }
  {
    float M = fmaxf(m0.w, m1.w); float a0 = __expf(m0.w - M), a1 = __expf(m1.w - M);
    r.w = (a0*p0.w + a1*p1.w) / (a0*l0.w + a1*l1.w);
  }
  *(float4*)&OUT[flat] = r;
}

/* ---- o-projection 64->128, swizzled store into k_up block-own prefixes:
   ofin[b][o][i][j] -> dout[b slab][plane o>>2][2i+((o>>1)&1)][2j+(o&1)] ---- */
__global__ __launch_bounds__(256) void k_oconv(const float* __restrict__ X,
    const float* __restrict__ OW, float* __restrict__ dout)
{
  __shared__ __align__(16) float Xs[64*64];    /* [cc][64 n] 16KB */
  __shared__ __align__(16) float wt[64*128];   /* [cc][o]    32KB */
  int b  = blockIdx.x / 144;
  int n0 = (blockIdx.x % 144) * 64;
  int t  = threadIdx.x;
  for (int idx = t; idx < 8192; idx += 256) {
    int cc = idx >> 7, o = idx & 127;
    wt[idx] = OW[o*64 + cc];
  }
  for (int idx = t; idx < 1024; idx += 256) {
    int cc = idx >> 4, wq = idx & 15;
    ((float4*)Xs)[idx] = *(const float4*)&X[((size_t)(b*64 + cc))*NN + n0 + wq*4];
  }
  __syncthreads();
  int n = t & 63, og = t >> 6;
  float acc[32];
  #pragma unroll
  for (int k = 0; k < 32; k++) acc[k] = 0.f;
  for (int cc = 0; cc < 64; cc++) {
    float xv = Xs[(cc << 6) + n];
    const float* wrow = wt + (cc << 7) + og*32;
    #pragma unroll
    for (int k = 0; k < 32; k++) acc[k] += wrow[k]*xv;
  }
  int ng = n0 + n;
  int i = ng / 96, j = ng - (ng/96)*96;
  #pragma unroll
  for (int k = 0; k < 32; k++) {
    int o = og*32 + k;
    size_t addr = (size_t)b*SLABF + (size_t)(o>>2)*HW
                + (size_t)(2*i + ((o>>1)&1))*192 + 2*j + (o&1);
    dout[addr] = acc[k];
  }
}

/* ---- up convtranspose + bias + gamma*y, f32, in-place (R6, unchanged) ---- */
__global__ __launch_bounds__(256) void k_up(float* __restrict__ dout,
    const float* __restrict__ upw, const float* __restrict__ upb,
    const float* __restrict__ Y, const float* __restrict__ gamma_p)
{
  __shared__ __align__(16) float o_s[128*24];   /* [c][24 j] 12KB */
  int blk = blockIdx.x;
  int jq = blk & 3;
  int r1 = blk >> 2;
  int i = r1 % 96, b = r1 / 96;
  int t = threadIdx.x;
  size_t slab = (size_t)b*SLABF;
  const float* src = dout + slab + (size_t)(2*i)*192 + jq*48;

  /* phase 0: unswizzle own quarter-prefix -> LDS (32 planes x 2 rows x 48) */
  for (int idx = t; idx < 3072; idx += 256) {
    int run = idx / 96, rem = idx - run*96;
    int r = rem / 48, cl = rem - r*48;
    float v = src[(size_t)run*HW + r*192 + cl];
    int o = 4*run + 2*r + (cl&1);
    o_s[o*24 + (cl>>1)] = v;
  }
  __syncthreads();

  int wv = t >> 6, lane = t & 63;
  int op = wv*32 + (lane & 31);     /* wave owns a 32-op band */
  int h6 = lane >> 5;               /* in-col half: [h6*12, +12) */
  float gm = *gamma_p;

  float a0[24], a1[24];             /* rows 2i / 2i+1, 24 out cols */
  #pragma unroll
  for (int k = 0; k < 24; k++) { a0[k] = 0.f; a1[k] = 0.f; }

  const float* wp = upw + (size_t)op*4;     /* stride 512 f32 per c */
  const float* xb = o_s + h6*12;
  for (int c = 0; c < 128; c++) {
    float4 wv4 = *(const float4*)(wp + (size_t)c*512);   /* w00 w01 w10 w11 */
    const float* xp = xb + c*24;
    float xv[12];
    *(float4*)&xv[0] = *(const float4*)(xp);
    *(float4*)&xv[4] = *(const float4*)(xp + 4);
    *(float4*)&xv[8] = *(const float4*)(xp + 8);
    #pragma unroll
    for (int m = 0; m < 12; m++) {
      a0[2*m]   += xv[m]*wv4.x;
      a0[2*m+1] += xv[m]*wv4.y;
      a1[2*m]   += xv[m]*wv4.z;
      a1[2*m+1] += xv[m]*wv4.w;
    }
  }

  float bias = upb[op];
  size_t obase = slab + (size_t)op*HW + (size_t)(2*i)*192 + jq*48 + h6*24;
  float* p0 = dout + obase;
  float* p1 = p0 + 192;
  const float* y0 = Y + obase;
  const float* y1 = y0 + 192;
  #pragma unroll
  for (int q = 0; q < 6; q++) {
    float4 ya = *(const float4*)(y0 + 4*q);
    float4 yb = *(const float4*)(y1 + 4*q);
    *(float4*)(p0 + 4*q) = make_float4(a0[4*q+0]+bias+gm*ya.x, a0[4*q+1]+bias+gm*ya.y,
                                       a0[4*q+2]+bias+gm*ya.z, a0[4*q+3]+bias+gm*ya.w);
    *(float4*)(p1 + 4*q) = make_float4(a1[4*q+0]+bias+gm*yb.x, a1[4*q+1]+bias+gm*yb.y,
                                       a1[4*q+2]+bias+gm*yb.z, a1[4*q+3]+bias+gm*yb.w);
  }
}

extern "C" void kernel_launch(void* const* d_in, const int* in_sizes, int n_in,
                              void* d_out, int out_size, void* d_ws, size_t ws_size,
                              hipStream_t stream) {
  const float* x_in  = (const float*)d_in[0];
  const float* y_in  = (const float*)d_in[1];
  const float* d0w   = (const float*)d_in[2];
  const float* d0b   = (const float*)d_in[3];
  const float* d1w   = (const float*)d_in[4];
  const float* d1b   = (const float*)d_in[5];
  const float* thw   = (const float*)d_in[6];
  const float* phw   = (const float*)d_in[7];
  const float* gw    = (const float*)d_in[8];
  const float* ow    = (const float*)d_in[9];
  const float* upw   = (const float*)d_in[10];
  const float* upb   = (const float*)d_in[11];
  const float* gamma = (const float*)d_in[12];
  float* out = (float*)d_out;

  /* d_ws UNUSED; d_in READ-ONLY; all scratch in d_out (see offset map). */
  k_down  <<<768,  256, 0, stream>>>(x_in, d0w, d0b, out + OFF_X);
  k_down  <<<768,  256, 0, stream>>>(y_in, d1w, d1b, out + OFF_Y);
  k_conv  <<<1152, 256, 0, stream>>>(out + OFF_X, thw, out + OFF_TH);
  k_conv  <<<1152, 256, 0, stream>>>(out + OFF_X, phw, out + OFF_TP);
  k_poolT <<<192,  256, 0, stream>>>(out + OFF_TP, (u16*)(out + OFF_PH));
  k_conv  <<<1152, 256, 0, stream>>>(out + OFF_Y, gw, out + OFF_TP);
  k_poolB <<<1152, 256, 0, stream>>>(out + OFF_TP, (u16*)(out + OFF_G));
  k_attn  <<<1152, 256, 0, stream>>>(out + OFF_TH, (const u16*)(out + OFF_PH),
                                     (const u16*)(out + OFF_G), out + OFF_X, out + OFF_Y);
  k_amerge<<<2304, 256, 0, stream>>>(out + OFF_X, out + OFF_Y, out + OFF_OM);
  k_oconv <<<576,  256, 0, stream>>>(out + OFF_OM, ow, out);
  k_up    <<<1536, 256, 0, stream>>>(out, upw, upb, y_in, gamma);
}

// Round 9
// 631.350 us; speedup vs baseline: 1.0419x; 1.0419x over previous
//
#include <hip/hip_runtime.h>
#include <hip/hip_bf16.h>

#define NN    9216      /* 96*96   */
#define MM    2304      /* 48*48   */
#define HW    36864     /* 192*192 */
#define SLABF 4718592   /* f32 per batch slab of output: 128*192*192 */
#define TEMPF 5.0f

/* d_out f32 offsets (scratch; lifetimes verified):
   x    [0        , 4718592)   dead after theta/phi convs; then attn PO partials
   y    [4718592  , 9437184)   dead after g conv; then attn m/l partials
   th   [9437184  , 11796480)  dead after attn
   tp   [11796480 , 14155776)  pre-pool temp, dead after pools
   ph   [14155776 , 14745600)  phiT bf16 [b][2304][64] (uses half region)
   g    [14745600 , 15335424)  g bf16 [b][64][2304]   (uses half region)
   omap [15335424 , 17694720)  merged attn out, read by oconv
   ofin : swizzled into plane-0..31 prefix of each batch slab (race-free k_up)
   Order: attn(writes PO@X, ML@Y) -> amerge(reads PO/ML, writes OM) ->
          oconv(reads OM, writes slab prefixes over X/Y/TH/PH/G) -> up. */
#define OFF_X   0
#define OFF_Y   4718592
#define OFF_TH  9437184
#define OFF_TP  11796480
#define OFF_PH  14155776
#define OFF_G   14745600
#define OFF_OM  15335424
#define POSZ    2359296   /* 4*64*9216: one split's partial O */
#define MLSZ    73728     /* 2*4*9216: m (or l) for both splits */

typedef unsigned short u16;
typedef unsigned int   u32;
typedef __attribute__((ext_vector_type(8))) short bf16x8;
typedef __attribute__((ext_vector_type(4))) float f32x4;

__device__ __forceinline__ u16 f2bf(float f){
  u32 u; __builtin_memcpy(&u,&f,4);
  u32 lsb = (u>>16)&1u; u += 0x7fffu + lsb;   /* RNE */
  return (u16)(u>>16);
}
__device__ __forceinline__ u32 pkbf(float a, float b){
  union { __hip_bfloat162 h; u32 u; } v;
  v.h = __float22bfloat162_rn(make_float2(a,b));
  return v.u;
}

/* ---- down conv k=2 s=2, 128->128, f32, LDS-tiled ----
   R8: R3 structure restored (reg-staged dbuf measured 104us; R7's
   global_load_lds prefetch serialized — compiler can't prove the in-flight
   LDS-writes don't alias the ds_reads of the other buffer (runtime buf), so
   it drains vmcnt(0) before compute -> stage no longer overlapped, 113us).
   ONLY isolated change vs R3: explicit fmaf chains. R3's
   "acc += a*b+c*d+e*f+g*h" compiled to 2mul+2fma+2add = 6 VALU/4 MACs
   (~144 ops/c); fmaf chain = 4 v_fmac (96/c), 1.5x issue cut. */
__global__ __launch_bounds__(256) void k_down(const float* __restrict__ in,
    const float* __restrict__ w, const float* __restrict__ bias, float* __restrict__ out)
{
  __shared__ __align__(16) float xs[2][6144];   /* [32 c][96 col][2 r] interleaved */
  int blk = blockIdx.x;
  int jt = blk & 1;
  int r1 = blk >> 1;
  int i  = r1 % 96; int b = r1 / 96;
  int t  = threadIdx.x;

  const float* src = in + (size_t)b*128*HW + (size_t)(2*i)*192 + jt*96;

  int cl[3], qq[3];
  #pragma unroll
  for (int k = 0; k < 3; k++) {
    int idx = t + k*256;
    cl[k] = idx / 24;
    qq[k] = idx - cl[k]*24;
  }

  float4 va[3], vb[3];
  #pragma unroll
  for (int k = 0; k < 3; k++) {
    const float* p = src + (size_t)cl[k]*HW + qq[k]*4;
    va[k] = *(const float4*)p;
    vb[k] = *(const float4*)(p + 192);
  }
  #pragma unroll
  for (int k = 0; k < 3; k++) {
    float* d = &xs[0][cl[k]*192 + qq[k]*8];
    *(float4*)d       = make_float4(va[k].x, vb[k].x, va[k].y, vb[k].y);
    *(float4*)(d + 4) = make_float4(va[k].z, vb[k].z, va[k].w, vb[k].w);
  }

  int og = t >> 3, jg = t & 7;       /* 32 og x 4 o ; 8 jg x 6 out cols */
  int o0 = og * 4;
  float acc[4][6];
  #pragma unroll
  for (int oo = 0; oo < 4; oo++)
    #pragma unroll
    for (int jj = 0; jj < 6; jj++) acc[oo][jj] = 0.f;

  const float* wbase = w + (size_t)o0*512;   /* w[o][c][4] */

  for (int ch = 0; ch < 4; ch++) {
    /* issue next chunk's global loads early (hide under compute) */
    if (ch < 3) {
      #pragma unroll
      for (int k = 0; k < 3; k++) {
        const float* p = src + (size_t)((ch+1)*32 + cl[k])*HW + qq[k]*4;
        va[k] = *(const float4*)p;
        vb[k] = *(const float4*)(p + 192);
      }
    }
    __syncthreads();                 /* chunk ch LDS writes visible */

    const float* xb = xs[ch & 1];
    const float* wc = wbase + (ch*32)*4;
    for (int c = 0; c < 32; c++) {
      const float* xp = xb + c*192 + jg*24;
      float4 x0 = *(const float4*)(xp);
      float4 x1 = *(const float4*)(xp + 4);
      float4 x2 = *(const float4*)(xp + 8);
      float4 x3 = *(const float4*)(xp + 12);
      float4 x4 = *(const float4*)(xp + 16);
      float4 x5 = *(const float4*)(xp + 20);
      const float* wp = wc + c*4;
      #pragma unroll
      for (int oo = 0; oo < 4; oo++) {
        float4 wv = *(const float4*)(wp + oo*512);   /* w00 w01 w10 w11 */
        float a;
        a=acc[oo][0]; a=fmaf(x0.x,wv.x,a); a=fmaf(x0.z,wv.y,a); a=fmaf(x0.y,wv.z,a); a=fmaf(x0.w,wv.w,a); acc[oo][0]=a;
        a=acc[oo][1]; a=fmaf(x1.x,wv.x,a); a=fmaf(x1.z,wv.y,a); a=fmaf(x1.y,wv.z,a); a=fmaf(x1.w,wv.w,a); acc[oo][1]=a;
        a=acc[oo][2]; a=fmaf(x2.x,wv.x,a); a=fmaf(x2.z,wv.y,a); a=fmaf(x2.y,wv.z,a); a=fmaf(x2.w,wv.w,a); acc[oo][2]=a;
        a=acc[oo][3]; a=fmaf(x3.x,wv.x,a); a=fmaf(x3.z,wv.y,a); a=fmaf(x3.y,wv.z,a); a=fmaf(x3.w,wv.w,a); acc[oo][3]=a;
        a=acc[oo][4]; a=fmaf(x4.x,wv.x,a); a=fmaf(x4.z,wv.y,a); a=fmaf(x4.y,wv.z,a); a=fmaf(x4.w,wv.w,a); acc[oo][4]=a;
        a=acc[oo][5]; a=fmaf(x5.x,wv.x,a); a=fmaf(x5.z,wv.y,a); a=fmaf(x5.y,wv.z,a); a=fmaf(x5.w,wv.w,a); acc[oo][5]=a;
      }
    }

    /* write next chunk into the other buffer, after compute (T14 split) */
    if (ch < 3) {
      #pragma unroll
      for (int k = 0; k < 3; k++) {
        float* d = &xs[(ch+1) & 1][cl[k]*192 + qq[k]*8];
        *(float4*)d       = make_float4(va[k].x, vb[k].x, va[k].y, vb[k].y);
        *(float4*)(d + 4) = make_float4(va[k].z, vb[k].z, va[k].w, vb[k].w);
      }
    }
  }

  /* epilogue: out[b][o][i][jt*48 + jg*6 + {0..5}] (8B-aligned float2 stores) */
  #pragma unroll
  for (int oo = 0; oo < 4; oo++) {
    int o = o0 + oo;
    float bv = bias[o];
    float* op = out + ((size_t)(b*128 + o))*NN + i*96 + jt*48 + jg*6;
    *(float2*)(op)     = make_float2(acc[oo][0] + bv, acc[oo][1] + bv);
    *(float2*)(op + 2) = make_float2(acc[oo][2] + bv, acc[oo][3] + bv);
    *(float2*)(op + 4) = make_float2(acc[oo][4] + bv, acc[oo][5] + bv);
  }
}

/* ---- 1x1 conv 128->64: out[b][cc][n] = sum_c W[cc][c]*X[b][c][n] ---- */
__global__ __launch_bounds__(256) void k_conv(const float* __restrict__ X,
    const float* __restrict__ WG, float* __restrict__ out)
{
  __shared__ __align__(16) float Xs[128*32];   /* [c][32 n] 16KB */
  __shared__ __align__(16) float wt[128*64];   /* [c][cc]   32KB */
  int b  = blockIdx.x / 288;
  int n0 = (blockIdx.x % 288) * 32;
  int t  = threadIdx.x;
  for (int idx = t; idx < 8192; idx += 256) {
    int c = idx >> 6, cc = idx & 63;
    wt[idx] = WG[cc*128 + c];
  }
  for (int idx = t; idx < 1024; idx += 256) {
    int c = idx >> 3, wq = idx & 7;
    ((float4*)Xs)[idx] = *(const float4*)&X[((size_t)(b*128 + c))*NN + n0 + wq*4];
  }
  __syncthreads();
  int n = t & 31, og = t >> 5;
  float acc[8];
  #pragma unroll
  for (int k = 0; k < 8; k++) acc[k] = 0.f;
  for (int c = 0; c < 128; c++) {
    float xv = Xs[(c<<5) + n];
    const float* wrow = wt + (c<<6) + og*8;
    float4 wa = *(const float4*)wrow;
    float4 wb = *(const float4*)(wrow + 4);
    acc[0]+=wa.x*xv; acc[1]+=wa.y*xv; acc[2]+=wa.z*xv; acc[3]+=wa.w*xv;
    acc[4]+=wb.x*xv; acc[5]+=wb.y*xv; acc[6]+=wb.z*xv; acc[7]+=wb.w*xv;
  }
  #pragma unroll
  for (int k = 0; k < 8; k++)
    out[((size_t)(b*64 + og*8 + k))*NN + n0 + n] = acc[k];
}

/* ---- phi path: 2x2 maxpool + transpose + bf16 cast.
   in: tp f32 [b][64][96][96] -> out: phiT bf16 [b][2304 k][64 c] ---- */
__global__ __launch_bounds__(256) void k_poolT(const float* __restrict__ in, u16* __restrict__ out)
{
  __shared__ float ps[48*68];    /* [J][cc] pad->68, 12.75KB */
  int blk = blockIdx.x;
  int I = blk % 48, b = blk / 48;
  int t = threadIdx.x;
  int cc = t >> 2, jq = t & 3;
  const float* base = in + ((size_t)(b*64 + cc))*NN + (size_t)(2*I)*96;
  #pragma unroll
  for (int j = 0; j < 12; j++) {
    int J = jq*12 + j;
    const float* p = base + 2*J;
    float2 a = *(const float2*)p;
    float2 c = *(const float2*)(p + 96);
    ps[J*68 + cc] = fmaxf(fmaxf(a.x, a.y), fmaxf(c.x, c.y));
  }
  __syncthreads();
  u32* op = (u32*)out + ((size_t)b*2304 + I*48)*32;   /* 48 rows x 32 u32 */
  for (int idx = t; idx < 1536; idx += 256) {
    int row = idx >> 5, pr = idx & 31;
    op[row*32 + pr] = pkbf(ps[row*68 + 2*pr], ps[row*68 + 2*pr + 1]);
  }
}

/* ---- g path: 2x2 maxpool + bf16 cast (layout preserved).
   in: tp f32 [b][64][96][96] -> out: g bf16 [b][64][2304]. ---- */
__global__ __launch_bounds__(256) void k_poolB(const float* __restrict__ in, u16* __restrict__ out)
{
  int t = blockIdx.x*256 + threadIdx.x;   /* 294912 */
  int pr = t % 24; int r = t / 24;
  int I = r % 48; r /= 48;
  int cc = r & 63, b = r >> 6;
  const float* p = in + ((size_t)(b*64 + cc))*NN + (size_t)(2*I)*96 + 4*pr;
  float4 r0 = *(const float4*)p;
  float4 r1 = *(const float4*)(p + 96);
  float m0 = fmaxf(fmaxf(r0.x, r0.y), fmaxf(r1.x, r1.y));
  float m1 = fmaxf(fmaxf(r0.z, r0.w), fmaxf(r1.z, r1.w));
  ((u32*)out)[((size_t)(b*64 + cc))*1152 + I*24 + pr] = pkbf(m0, m1);
}

/* ---- MFMA flash attention, split-K x2 (bf16 inputs pre-converted).
   grid = b(4) x ks(2) x qtile(144) = 1152 blocks (~4.5/CU, LDS cap 5).
   Outputs UNNORMALIZED partial O to PO[ks], (m,l) to ML; k_amerge combines. ---- */
__global__ __launch_bounds__(256) void k_attn(const float* __restrict__ TH,
    const u16* __restrict__ PHT, const u16* __restrict__ GB,
    float* __restrict__ PO, float* __restrict__ ML)
{
  __shared__ __align__(16) u16 sm[13824];   /* 27648 B */
  int t = threadIdx.x;
  int lane = t & 63, wv = t >> 6;
  int quad = lane >> 4, l15 = lane & 15;
  int id = blockIdx.x;
  int b   = id / 288;
  int rem = id % 288;
  int ks  = rem / 144;
  int q0  = (rem % 144) * 64;
  int qw  = q0 + wv*16;

  /* theta A-fragments, TEMP pre-scaled: A[q=l15][c=half*32+quad*8+j] */
  bf16x8 afrag[2];
  #pragma unroll
  for (int h = 0; h < 2; h++)
    #pragma unroll
    for (int j = 0; j < 8; j++) {
      float v = TEMPF * TH[((size_t)(b*64 + h*32 + quad*8 + j))*NN + qw + l15];
      afrag[h][j] = (short)f2bf(v);
    }

  f32x4 oacc[4];
  #pragma unroll
  for (int ct = 0; ct < 4; ct++)
    #pragma unroll
    for (int r = 0; r < 4; r++) oacc[ct][r] = 0.f;
  float m_r[4], l_r[4];
  #pragma unroll
  for (int r = 0; r < 4; r++) { m_r[r] = -3.0e38f; l_r[r] = 0.f; }

  int k0end = ks*1152 + 1152;
  for (int k0 = ks*1152; k0 < k0end; k0 += 64) {
    __syncthreads();                       /* prev PV done before overwrite */
    /* stage phi_T[k][c]: 64 rows x 128B, 2 uint4/thread, fully coalesced */
    #pragma unroll
    for (int s = 0; s < 2; s++) {
      int idx = t + s*256;
      int row = idx >> 3, q = idx & 7;
      uint4 v = ((const uint4*)(PHT + ((size_t)(b*2304 + k0 + row))*64))[q];
      *(uint4*)&sm[row*72 + q*8] = v;
    }
    /* stage g[cc][k]: 64 rows x 128B */
    #pragma unroll
    for (int s = 0; s < 2; s++) {
      int idx = t + s*256;
      int row = idx >> 3, q = idx & 7;
      uint4 v = *(const uint4*)(GB + (size_t)(b*64 + row)*2304 + k0 + q*8);
      *(uint4*)&sm[4608 + row*72 + q*8] = v;
    }
    __syncthreads();

    /* QK^T: 4 key-tiles x (2 MFMA over c) -> S[q=quad*4+r][key=kt*16+l15] */
    f32x4 s[4];
    #pragma unroll
    for (int kt = 0; kt < 4; kt++) {
      f32x4 acc;
      #pragma unroll
      for (int r = 0; r < 4; r++) acc[r] = 0.f;
      #pragma unroll
      for (int h = 0; h < 2; h++) {
        bf16x8 bfrag = *(const bf16x8*)&sm[(kt*16 + l15)*72 + h*32 + quad*8];
        acc = __builtin_amdgcn_mfma_f32_16x16x32_bf16(afrag[h], bfrag, acc, 0, 0, 0);
      }
      s[kt] = acc;
    }

    /* online softmax, per row r (q = quad*4+r), reduce over 16 lanes + 4 tiles */
    float al[4];
    #pragma unroll
    for (int r = 0; r < 4; r++) {
      float mx = fmaxf(fmaxf(s[0][r], s[1][r]), fmaxf(s[2][r], s[3][r]));
      #pragma unroll
      for (int d = 1; d < 16; d <<= 1) mx = fmaxf(mx, __shfl_xor(mx, d));
      float mn = fmaxf(m_r[r], mx);
      float a  = __expf(m_r[r] - mn);
      m_r[r] = mn;
      float ps = 0.f;
      #pragma unroll
      for (int kt = 0; kt < 4; kt++) {
        float p = __expf(s[kt][r] - mn);
        s[kt][r] = p; ps += p;
      }
      #pragma unroll
      for (int d = 1; d < 16; d <<= 1) ps += __shfl_xor(ps, d);
      l_r[r] = l_r[r]*a + ps;
      al[r] = a;
    }
    /* P -> per-wave LDS (bf16), rescale O */
    #pragma unroll
    for (int kt = 0; kt < 4; kt++)
      #pragma unroll
      for (int r = 0; r < 4; r++)
        sm[9216 + wv*1152 + (quad*4 + r)*72 + kt*16 + l15] = f2bf(s[kt][r]);
    #pragma unroll
    for (int ct = 0; ct < 4; ct++)
      #pragma unroll
      for (int r = 0; r < 4; r++) oacc[ct][r] *= al[r];

    /* PV: A = P[q=l15][key=h*32+quad*8+j], B = g[key][cc=ct*16+l15] */
    bf16x8 pf[2];
    #pragma unroll
    for (int h = 0; h < 2; h++)
      pf[h] = *(const bf16x8*)&sm[9216 + wv*1152 + l15*72 + h*32 + quad*8];
    #pragma unroll
    for (int ct = 0; ct < 4; ct++)
      #pragma unroll
      for (int h = 0; h < 2; h++) {
        bf16x8 gf = *(const bf16x8*)&sm[4608 + (ct*16 + l15)*72 + h*32 + quad*8];
        oacc[ct] = __builtin_amdgcn_mfma_f32_16x16x32_bf16(pf[h], gf, oacc[ct], 0, 0, 0);
      }
  }

  __syncthreads();   /* all waves done with phi/g/P regions */
  /* m,l per query (one lane per row) */
  if (l15 == 0) {
    #pragma unroll
    for (int r = 0; r < 4; r++) {
      int qg = qw + quad*4 + r;
      ML[(size_t)(ks*4 + b)*9216 + qg]         = m_r[r];
      ML[MLSZ + (size_t)(ks*4 + b)*9216 + qg]  = l_r[r];
    }
  }
  /* raw (unnormalized) O, transposed through LDS for coalesced store */
  float* ol = (float*)sm + wv*1280;      /* [cc 64][20] */
  #pragma unroll
  for (int ct = 0; ct < 4; ct++)
    #pragma unroll
    for (int r = 0; r < 4; r++)
      ol[(ct*16 + l15)*20 + quad*4 + r] = oacc[ct][r];
  __syncthreads();
  const float* orow = ol + lane*20;      /* cc = lane */
  float4 v0 = *(const float4*)(orow);
  float4 v1 = *(const float4*)(orow + 4);
  float4 v2 = *(const float4*)(orow + 8);
  float4 v3 = *(const float4*)(orow + 12);
  float* dst = PO + (size_t)ks*POSZ + ((size_t)(b*64 + lane))*NN + qw;
  *(float4*)(dst)      = v0;
  *(float4*)(dst + 4)  = v1;
  *(float4*)(dst + 8)  = v2;
  *(float4*)(dst + 12) = v3;
}

/* ---- combine 2 split-K partials: O = sum(e^{mi-M} POi) / sum(e^{mi-M} li) ---- */
__global__ __launch_bounds__(256) void k_amerge(const float* __restrict__ PO,
    const float* __restrict__ ML, float* __restrict__ OUT)
{
  int idx = blockIdx.x*256 + threadIdx.x;   /* 589824 float4s */
  size_t flat = (size_t)idx*4;
  int bc = (int)(flat / NN);
  int n  = (int)(flat - (size_t)bc*NN);
  int b  = bc >> 6;
  float4 p0 = *(const float4*)&PO[flat];
  float4 p1 = *(const float4*)&PO[POSZ + flat];
  const float* m0p = ML + (size_t)b*9216 + n;
  const float* m1p = ML + (size_t)(4 + b)*9216 + n;
  const float* l0p = ML + MLSZ + (size_t)b*9216 + n;
  const float* l1p = ML + MLSZ + (size_t)(4 + b)*9216 + n;
  float4 m0 = *(const float4*)m0p, m1 = *(const float4*)m1p;
  float4 l0 = *(const float4*)l0p, l1 = *(const float4*)l1p;
  float4 r;
  {
    float M = fmaxf(m0.x, m1.x); float a0 = __expf(m0.x - M), a1 = __expf(m1.x - M);
    r.x = (a0*p0.x + a1*p1.x) / (a0*l0.x + a1*l1.x);
  }
  {
    float M = fmaxf(m0.y, m1.y); float a0 = __expf(m0.y - M), a1 = __expf(m1.y - M);
    r.y = (a0*p0.y + a1*p1.y) / (a0*l0.y + a1*l1.y);
  }
  {
    float M = fmaxf(m0.z, m1.z); float a0 = __expf(m0.z - M), a1 = __expf(m1.z - M);
    r.z = (a0*p0.z + a1*p1.z) / (a0*l0.z + a1*l1.z);
  }
  {
    float M = fmaxf(m0.w, m1.w); float a0 = __expf(m0.w - M), a1 = __expf(m1.w - M);
    r.w = (a0*p0.w + a1*p1.w) / (a0*l0.w + a1*l1.w);
  }
  *(float4*)&OUT[flat] = r;
}

/* ---- o-projection 64->128, swizzled store into k_up block-own prefixes:
   ofin[b][o][i][j] -> dout[b slab][plane o>>2][2i+((o>>1)&1)][2j+(o&1)] ---- */
__global__ __launch_bounds__(256) void k_oconv(const float* __restrict__ X,
    const float* __restrict__ OW, float* __restrict__ dout)
{
  __shared__ __align__(16) float Xs[64*64];    /* [cc][64 n] 16KB */
  __shared__ __align__(16) float wt[64*128];   /* [cc][o]    32KB */
  int b  = blockIdx.x / 144;
  int n0 = (blockIdx.x % 144) * 64;
  int t  = threadIdx.x;
  for (int idx = t; idx < 8192; idx += 256) {
    int cc = idx >> 7, o = idx & 127;
    wt[idx] = OW[o*64 + cc];
  }
  for (int idx = t; idx < 1024; idx += 256) {
    int cc = idx >> 4, wq = idx & 15;
    ((float4*)Xs)[idx] = *(const float4*)&X[((size_t)(b*64 + cc))*NN + n0 + wq*4];
  }
  __syncthreads();
  int n = t & 63, og = t >> 6;
  float acc[32];
  #pragma unroll
  for (int k = 0; k < 32; k++) acc[k] = 0.f;
  for (int cc = 0; cc < 64; cc++) {
    float xv = Xs[(cc << 6) + n];
    const float* wrow = wt + (cc << 7) + og*32;
    #pragma unroll
    for (int k = 0; k < 32; k++) acc[k] += wrow[k]*xv;
  }
  int ng = n0 + n;
  int i = ng / 96, j = ng - (ng/96)*96;
  #pragma unroll
  for (int k = 0; k < 32; k++) {
    int o = og*32 + k;
    size_t addr = (size_t)b*SLABF + (size_t)(o>>2)*HW
                + (size_t)(2*i + ((o>>1)&1))*192 + 2*j + (o&1);
    dout[addr] = acc[k];
  }
}

/* ---- up convtranspose + bias + gamma*y, f32, in-place (R6, unchanged) ---- */
__global__ __launch_bounds__(256) void k_up(float* __restrict__ dout,
    const float* __restrict__ upw, const float* __restrict__ upb,
    const float* __restrict__ Y, const float* __restrict__ gamma_p)
{
  __shared__ __align__(16) float o_s[128*24];   /* [c][24 j] 12KB */
  int blk = blockIdx.x;
  int jq = blk & 3;
  int r1 = blk >> 2;
  int i = r1 % 96, b = r1 / 96;
  int t = threadIdx.x;
  size_t slab = (size_t)b*SLABF;
  const float* src = dout + slab + (size_t)(2*i)*192 + jq*48;

  /* phase 0: unswizzle own quarter-prefix -> LDS (32 planes x 2 rows x 48) */
  for (int idx = t; idx < 3072; idx += 256) {
    int run = idx / 96, rem = idx - run*96;
    int r = rem / 48, cl = rem - r*48;
    float v = src[(size_t)run*HW + r*192 + cl];
    int o = 4*run + 2*r + (cl&1);
    o_s[o*24 + (cl>>1)] = v;
  }
  __syncthreads();

  int wv = t >> 6, lane = t & 63;
  int op = wv*32 + (lane & 31);     /* wave owns a 32-op band */
  int h6 = lane >> 5;               /* in-col half: [h6*12, +12) */
  float gm = *gamma_p;

  float a0[24], a1[24];             /* rows 2i / 2i+1, 24 out cols */
  #pragma unroll
  for (int k = 0; k < 24; k++) { a0[k] = 0.f; a1[k] = 0.f; }

  const float* wp = upw + (size_t)op*4;     /* stride 512 f32 per c */
  const float* xb = o_s + h6*12;
  for (int c = 0; c < 128; c++) {
    float4 wv4 = *(const float4*)(wp + (size_t)c*512);   /* w00 w01 w10 w11 */
    const float* xp = xb + c*24;
    float xv[12];
    *(float4*)&xv[0] = *(const float4*)(xp);
    *(float4*)&xv[4] = *(const float4*)(xp + 4);
    *(float4*)&xv[8] = *(const float4*)(xp + 8);
    #pragma unroll
    for (int m = 0; m < 12; m++) {
      a0[2*m]   += xv[m]*wv4.x;
      a0[2*m+1] += xv[m]*wv4.y;
      a1[2*m]   += xv[m]*wv4.z;
      a1[2*m+1] += xv[m]*wv4.w;
    }
  }

  float bias = upb[op];
  size_t obase = slab + (size_t)op*HW + (size_t)(2*i)*192 + jq*48 + h6*24;
  float* p0 = dout + obase;
  float* p1 = p0 + 192;
  const float* y0 = Y + obase;
  const float* y1 = y0 + 192;
  #pragma unroll
  for (int q = 0; q < 6; q++) {
    float4 ya = *(const float4*)(y0 + 4*q);
    float4 yb = *(const float4*)(y1 + 4*q);
    *(float4*)(p0 + 4*q) = make_float4(a0[4*q+0]+bias+gm*ya.x, a0[4*q+1]+bias+gm*ya.y,
                                       a0[4*q+2]+bias+gm*ya.z, a0[4*q+3]+bias+gm*ya.w);
    *(float4*)(p1 + 4*q) = make_float4(a1[4*q+0]+bias+gm*yb.x, a1[4*q+1]+bias+gm*yb.y,
                                       a1[4*q+2]+bias+gm*yb.z, a1[4*q+3]+bias+gm*yb.w);
  }
}

extern "C" void kernel_launch(void* const* d_in, const int* in_sizes, int n_in,
                              void* d_out, int out_size, void* d_ws, size_t ws_size,
                              hipStream_t stream) {
  const float* x_in  = (const float*)d_in[0];
  const float* y_in  = (const float*)d_in[1];
  const float* d0w   = (const float*)d_in[2];
  const float* d0b   = (const float*)d_in[3];
  const float* d1w   = (const float*)d_in[4];
  const float* d1b   = (const float*)d_in[5];
  const float* thw   = (const float*)d_in[6];
  const float* phw   = (const float*)d_in[7];
  const float* gw    = (const float*)d_in[8];
  const float* ow    = (const float*)d_in[9];
  const float* upw   = (const float*)d_in[10];
  const float* upb   = (const float*)d_in[11];
  const float* gamma = (const float*)d_in[12];
  float* out = (float*)d_out;

  /* d_ws UNUSED; d_in READ-ONLY; all scratch in d_out (see offset map). */
  k_down  <<<768,  256, 0, stream>>>(x_in, d0w, d0b, out + OFF_X);
  k_down  <<<768,  256, 0, stream>>>(y_in, d1w, d1b, out + OFF_Y);
  k_conv  <<<1152, 256, 0, stream>>>(out + OFF_X, thw, out + OFF_TH);
  k_conv  <<<1152, 256, 0, stream>>>(out + OFF_X, phw, out + OFF_TP);
  k_poolT <<<192,  256, 0, stream>>>(out + OFF_TP, (u16*)(out + OFF_PH));
  k_conv  <<<1152, 256, 0, stream>>>(out + OFF_Y, gw, out + OFF_TP);
  k_poolB <<<1152, 256, 0, stream>>>(out + OFF_TP, (u16*)(out + OFF_G));
  k_attn  <<<1152, 256, 0, stream>>>(out + OFF_TH, (const u16*)(out + OFF_PH),
                                     (const u16*)(out + OFF_G), out + OFF_X, out + OFF_Y);
  k_amerge<<<2304, 256, 0, stream>>>(out + OFF_X, out + OFF_Y, out + OFF_OM);
  k_oconv <<<576,  256, 0, stream>>>(out + OFF_OM, ow, out);
  k_up    <<<1536, 256, 0, stream>>>(out, upw, upb, y_in, gamma);
}